// Round 2
// baseline (3126.780 us; speedup 1.0000x reference)
//
#include <hip/hip_runtime.h>
#include <math.h>

// Shapes
// B=2048 S=64 D=6 H=4 DM=64 SS=150 A=7 HID=256 FF=256 DH=16
#define NB 2048
#define LDW 68

#define LD4(p) (*(const float4*)(p))
// NOTE: macro param must NOT be named x/y/z/w — preprocessor would substitute
// inside the member access (.w) too.
#define FMA4(ac, s, vv) { ac[0] = fmaf((s), (vv).x, ac[0]); ac[1] = fmaf((s), (vv).y, ac[1]); \
                          ac[2] = fmaf((s), (vv).z, ac[2]); ac[3] = fmaf((s), (vv).w, ac[3]); }

// out layout (floats): mu[14336] std[14336] seq[19660800] mem[50331648] len[2048]
#define O_STD 14336
#define O_SEQ 28672
#define O_MEM 19689472
#define O_LEN 70021120

__global__ __launch_bounds__(256) void copy4_kernel(const float4* __restrict__ src,
                                                    float4* __restrict__ dst, int n) {
    int i = blockIdx.x * 256 + threadIdx.x;
    if (i < n) dst[i] = src[i];
}

__global__ __launch_bounds__(256) void obs_ln_kernel(const float* __restrict__ obs,
        const float* __restrict__ g, const float* __restrict__ be,
        const int* __restrict__ len, float* __restrict__ outSeq, float* __restrict__ outLen) {
    int w = threadIdx.x >> 6, lane = threadIdx.x & 63;
    int b = blockIdx.x * 4 + w;
    const float* row = obs + (size_t)b * 150;
    float v0 = row[lane], v1 = row[64 + lane];
    float v2 = (lane < 22) ? row[128 + lane] : 0.f;
    float s = v0 + v1 + v2;
    #pragma unroll
    for (int m = 1; m <= 32; m <<= 1) s += __shfl_xor(s, m);
    float mean = s * (1.0f / 150.0f);
    float d0 = v0 - mean, d1 = v1 - mean;
    float d2 = (lane < 22) ? (v2 - mean) : 0.f;
    float q = d0 * d0 + d1 * d1 + d2 * d2;
    #pragma unroll
    for (int m = 1; m <= 32; m <<= 1) q += __shfl_xor(q, m);
    float rs = rsqrtf(q * (1.0f / 150.0f) + 1e-5f);
    int lenraw = len[b];
    int lidx = min(max(lenraw, 0), 63);
    float* orow = outSeq + ((size_t)lidx * NB + b) * 150;
    orow[lane]      = d0 * rs * g[lane] + be[lane];
    orow[64 + lane] = d1 * rs * g[64 + lane] + be[64 + lane];
    if (lane < 22) orow[128 + lane] = d2 * rs * g[128 + lane] + be[128 + lane];
    if (lane == 0) outLen[b] = (float)((lenraw + 1) & 63);
}

__device__ __forceinline__ void ln_tile(const float x[4][4], float* __restrict__ dst,
        const float* __restrict__ g, const float* __restrict__ be, int r0, int c0) {
    #pragma unroll
    for (int i = 0; i < 4; ++i) {
        float s = x[i][0] + x[i][1] + x[i][2] + x[i][3];
        s += __shfl_xor(s, 1); s += __shfl_xor(s, 2); s += __shfl_xor(s, 4); s += __shfl_xor(s, 8);
        float m = s * 0.015625f;
        float d0 = x[i][0] - m, d1 = x[i][1] - m, d2 = x[i][2] - m, d3 = x[i][3] - m;
        float q = d0 * d0 + d1 * d1 + d2 * d2 + d3 * d3;
        q += __shfl_xor(q, 1); q += __shfl_xor(q, 2); q += __shfl_xor(q, 4); q += __shfl_xor(q, 8);
        float rs = rsqrtf(q * 0.015625f + 1e-5f);
        float4 o;
        o.x = d0 * rs * g[c0 + 0] + be[c0 + 0];
        o.y = d1 * rs * g[c0 + 1] + be[c0 + 1];
        o.z = d2 * rs * g[c0 + 2] + be[c0 + 2];
        o.w = d3 * rs * g[c0 + 3] + be[c0 + 3];
        *(float4*)&dst[(r0 + i) * LDW + c0] = o;
    }
}

// acc[4][4] += A[r0..r0+3][:] @ W[:][c0..c0+3], both LDS stride LDW, K=64
__device__ __forceinline__ void gemm64_acc(float acc[4][4],
        const float* __restrict__ A, const float* __restrict__ W, int r0, int c0) {
    #pragma unroll
    for (int k0 = 0; k0 < 64; k0 += 4) {
        float4 a0 = LD4(&A[(r0 + 0) * LDW + k0]);
        float4 a1 = LD4(&A[(r0 + 1) * LDW + k0]);
        float4 a2 = LD4(&A[(r0 + 2) * LDW + k0]);
        float4 a3 = LD4(&A[(r0 + 3) * LDW + k0]);
        float4 w0 = LD4(&W[(k0 + 0) * LDW + c0]);
        float4 w1 = LD4(&W[(k0 + 1) * LDW + c0]);
        float4 w2 = LD4(&W[(k0 + 2) * LDW + c0]);
        float4 w3 = LD4(&W[(k0 + 3) * LDW + c0]);
        FMA4(acc[0], a0.x, w0); FMA4(acc[0], a0.y, w1); FMA4(acc[0], a0.z, w2); FMA4(acc[0], a0.w, w3);
        FMA4(acc[1], a1.x, w0); FMA4(acc[1], a1.y, w1); FMA4(acc[1], a1.z, w2); FMA4(acc[1], a1.w, w3);
        FMA4(acc[2], a2.x, w0); FMA4(acc[2], a2.y, w1); FMA4(acc[2], a2.z, w2); FMA4(acc[2], a2.w, w3);
        FMA4(acc[3], a3.x, w0); FMA4(acc[3], a3.y, w1); FMA4(acc[3], a3.z, w2); FMA4(acc[3], a3.w, w3);
    }
}

__global__ __launch_bounds__(256, 2) void mega_kernel(
        const float* __restrict__ seq,      // updated seq (S,B,150) in d_out
        const float* __restrict__ memory,   // (D,B,S,DM)
        const int* __restrict__ len,
        const float* __restrict__ Wemb,
        const float* __restrict__ ln1g, const float* __restrict__ ln1b,
        const float* __restrict__ ln2g, const float* __restrict__ ln2b,
        const float* __restrict__ Wq, const float* __restrict__ Wk,
        const float* __restrict__ Wv, const float* __restrict__ Wo,
        const float* __restrict__ W1, const float* __restrict__ b1,
        const float* __restrict__ W2, const float* __restrict__ b2,
        float* __restrict__ memOut, float* __restrict__ xrow) {
    __shared__ float uni[19456];
    __shared__ float sLn[256];
    __shared__ float sB1[256];
    __shared__ float sB2[64];
    float* const sH = uni;            // [64][68]
    float* const sM = uni + 4352;     // [64][68]  (also FF temp T)
    float* const sW = uni + 8704;     // [64][68]  (weight staging; head slices use stride 20)
    float* const sQ = uni + 13056;    // [64][20]
    float* const sK = uni + 14336;    // [128][20]
    float* const sV = uni + 16896;    // [128][20]
    float* const sSeq = uni;          // [64][152] (embed phase)
    float* const sWe  = uni + 9728;   // [152][64] (embed phase)

    const int tid = threadIdx.x;
    const int b = blockIdx.x;
    const int tr = tid >> 4, tc = tid & 15;
    const int r0 = tr << 2, c0 = tc << 2;
    const int qq = tid >> 2, jj = tid & 3;

    const int lenraw = len[b];
    const int lidx = min(max(lenraw, 0), 63);
    const bool reset = (((lenraw + 1) & 63) == 0);

    // ---------- embedding: x = seq_b(64x150) @ Wemb(150x64) ----------
    for (int idx = tid; idx < 9728; idx += 256) {
        int r = idx / 152, e = idx - r * 152;
        sSeq[idx] = (e < 150) ? seq[((size_t)r * NB + b) * 150 + e] : 0.f;
    }
    for (int idx = tid; idx < 9728; idx += 256) {
        int r = idx >> 6, c = idx & 63;
        sWe[idx] = (r < 150) ? Wemb[r * 64 + c] : 0.f;
    }
    __syncthreads();
    float x[4][4];
    #pragma unroll
    for (int i = 0; i < 4; ++i) { x[i][0] = 0.f; x[i][1] = 0.f; x[i][2] = 0.f; x[i][3] = 0.f; }
    #pragma unroll 4
    for (int k0 = 0; k0 < 152; k0 += 4) {
        float4 a0 = LD4(&sSeq[(r0 + 0) * 152 + k0]);
        float4 a1 = LD4(&sSeq[(r0 + 1) * 152 + k0]);
        float4 a2 = LD4(&sSeq[(r0 + 2) * 152 + k0]);
        float4 a3 = LD4(&sSeq[(r0 + 3) * 152 + k0]);
        float4 w0 = LD4(&sWe[(k0 + 0) * 64 + c0]);
        float4 w1 = LD4(&sWe[(k0 + 1) * 64 + c0]);
        float4 w2 = LD4(&sWe[(k0 + 2) * 64 + c0]);
        float4 w3 = LD4(&sWe[(k0 + 3) * 64 + c0]);
        FMA4(x[0], a0.x, w0); FMA4(x[0], a0.y, w1); FMA4(x[0], a0.z, w2); FMA4(x[0], a0.w, w3);
        FMA4(x[1], a1.x, w0); FMA4(x[1], a1.y, w1); FMA4(x[1], a1.z, w2); FMA4(x[1], a1.w, w3);
        FMA4(x[2], a2.x, w0); FMA4(x[2], a2.y, w1); FMA4(x[2], a2.z, w2); FMA4(x[2], a2.w, w3);
        FMA4(x[3], a3.x, w0); FMA4(x[3], a3.y, w1); FMA4(x[3], a3.z, w2); FMA4(x[3], a3.w, w3);
    }

    // ---------- 6 transformer layers ----------
    #pragma unroll 1
    for (int l = 0; l < 6; ++l) {
        __syncthreads();   // protect smalls/sM/uni from previous phase readers
        if (tid < 64) {
            sLn[tid]       = ln1g[l * 64 + tid];
            sLn[64 + tid]  = ln1b[l * 64 + tid];
            sLn[128 + tid] = ln2g[l * 64 + tid];
            sLn[192 + tid] = ln2b[l * 64 + tid];
            sB2[tid]       = b2[l * 64 + tid];
        }
        sB1[tid] = b1[l * 256 + tid];
        const float* gmem = memory + ((size_t)l * NB + b) * 4096;
        #pragma unroll
        for (int jq = 0; jq < 4; ++jq) {
            int qi = tid + jq * 256;
            int r = qi >> 4, cq = (qi & 15) << 2;
            *(float4*)&sM[r * LDW + cq] = LD4(&gmem[r * 64 + cq]);
        }
        __syncthreads();

        // mem_out[l][b] = reset ? x : memory[l][b]
        float* gout = memOut + ((size_t)l * NB + b) * 4096;
        #pragma unroll
        for (int i = 0; i < 4; ++i) {
            float4 v;
            if (reset) { v.x = x[i][0]; v.y = x[i][1]; v.z = x[i][2]; v.w = x[i][3]; }
            else v = LD4(&sM[(r0 + i) * LDW + c0]);
            *(float4*)&gout[(r0 + i) * 64 + c0] = v;
        }

        // h = LN1(x) -> sH
        ln_tile(x, sH, sLn, sLn + 64, r0, c0);
        __syncthreads();

        // attention, per head
        float aoc[4][4];
        #pragma unroll
        for (int h = 0; h < 4; ++h) {
            { // stage Wq/Wk/Wv column slices (64x16 each), stride 20
                int k = tid >> 2, dq = (tid & 3) << 2;
                size_t gb = (size_t)l * 4096 + k * 64 + h * 16 + dq;
                *(float4*)&sW[k * 20 + dq]        = LD4(&Wq[gb]);
                *(float4*)&sW[1280 + k * 20 + dq] = LD4(&Wk[gb]);
                *(float4*)&sW[2560 + k * 20 + dq] = LD4(&Wv[gb]);
            }
            __syncthreads();
            { // q_h = sH @ Wq_slice  -> sQ[64][16]; thread (qq,jj) does 4 cols
                float ac[4] = {0.f, 0.f, 0.f, 0.f};
                int cc = jj << 2;
                #pragma unroll
                for (int k0 = 0; k0 < 64; k0 += 4) {
                    float4 a = LD4(&sH[qq * LDW + k0]);
                    { float4 w = LD4(&sW[(k0 + 0) * 20 + cc]); FMA4(ac, a.x, w); }
                    { float4 w = LD4(&sW[(k0 + 1) * 20 + cc]); FMA4(ac, a.y, w); }
                    { float4 w = LD4(&sW[(k0 + 2) * 20 + cc]); FMA4(ac, a.z, w); }
                    { float4 w = LD4(&sW[(k0 + 3) * 20 + cc]); FMA4(ac, a.w, w); }
                }
                *(float4*)&sQ[qq * 20 + cc] = make_float4(ac[0], ac[1], ac[2], ac[3]);
            }
            { // k_h, v_h over kv_in = [mem; h] (128x64) -> sK/sV[128][16]
                int j = tid >> 1, ch = (tid & 1) << 3;
                const float* arow = (j < 64) ? &sM[j * LDW] : &sH[(j - 64) * LDW];
                float kc0[4] = {0,0,0,0}, kc1[4] = {0,0,0,0};
                float vc0[4] = {0,0,0,0}, vc1[4] = {0,0,0,0};
                #pragma unroll
                for (int k0 = 0; k0 < 64; k0 += 4) {
                    float4 a = LD4(&arow[k0]);
                    #pragma unroll
                    for (int kk = 0; kk < 4; ++kk) {
                        float s = (kk == 0) ? a.x : (kk == 1) ? a.y : (kk == 2) ? a.z : a.w;
                        const float* wk = &sW[1280 + (k0 + kk) * 20 + ch];
                        const float* wv = &sW[2560 + (k0 + kk) * 20 + ch];
                        float4 ka = LD4(wk), kb2 = LD4(wk + 4);
                        float4 va = LD4(wv), vb = LD4(wv + 4);
                        FMA4(kc0, s, ka); FMA4(kc1, s, kb2);
                        FMA4(vc0, s, va); FMA4(vc1, s, vb);
                    }
                }
                *(float4*)&sK[j * 20 + ch]     = make_float4(kc0[0], kc0[1], kc0[2], kc0[3]);
                *(float4*)&sK[j * 20 + ch + 4] = make_float4(kc1[0], kc1[1], kc1[2], kc1[3]);
                *(float4*)&sV[j * 20 + ch]     = make_float4(vc0[0], vc0[1], vc0[2], vc0[3]);
                *(float4*)&sV[j * 20 + ch + 4] = make_float4(vc1[0], vc1[1], vc1[2], vc1[3]);
            }
            __syncthreads();
            // scores + softmax + @v, registers; thread (qq, jj) owns j = jj + 4*i
            float qv[16];
            #pragma unroll
            for (int d4 = 0; d4 < 4; ++d4) {
                float4 t = LD4(&sQ[qq * 20 + (d4 << 2)]);
                qv[d4 * 4 + 0] = t.x; qv[d4 * 4 + 1] = t.y; qv[d4 * 4 + 2] = t.z; qv[d4 * 4 + 3] = t.w;
            }
            float p[32]; float mx = -INFINITY;
            #pragma unroll
            for (int i = 0; i < 32; ++i) {
                int j = jj + (i << 2);
                const float* kr = &sK[j * 20];
                float s = 0.f;
                #pragma unroll
                for (int d4 = 0; d4 < 4; ++d4) {
                    float4 k4 = LD4(&kr[d4 << 2]);
                    s = fmaf(qv[d4 * 4 + 0], k4.x, s); s = fmaf(qv[d4 * 4 + 1], k4.y, s);
                    s = fmaf(qv[d4 * 4 + 2], k4.z, s); s = fmaf(qv[d4 * 4 + 3], k4.w, s);
                }
                s *= 0.25f;
                if (j >= 64 && (j - 64) > qq) s = -INFINITY;
                p[i] = s; mx = fmaxf(mx, s);
            }
            mx = fmaxf(mx, __shfl_xor(mx, 1));
            mx = fmaxf(mx, __shfl_xor(mx, 2));
            float sm = 0.f;
            #pragma unroll
            for (int i = 0; i < 32; ++i) { p[i] = __expf(p[i] - mx); sm += p[i]; }
            sm += __shfl_xor(sm, 1); sm += __shfl_xor(sm, 2);
            float inv = 1.0f / sm;
            float oc[16];
            #pragma unroll
            for (int d = 0; d < 16; ++d) oc[d] = 0.f;
            #pragma unroll
            for (int i = 0; i < 32; ++i) {
                int j = jj + (i << 2);
                float pv = p[i];
                const float* vr = &sV[j * 20];
                #pragma unroll
                for (int d4 = 0; d4 < 4; ++d4) {
                    float4 v4 = LD4(&vr[d4 << 2]);
                    oc[d4 * 4 + 0] = fmaf(pv, v4.x, oc[d4 * 4 + 0]);
                    oc[d4 * 4 + 1] = fmaf(pv, v4.y, oc[d4 * 4 + 1]);
                    oc[d4 * 4 + 2] = fmaf(pv, v4.z, oc[d4 * 4 + 2]);
                    oc[d4 * 4 + 3] = fmaf(pv, v4.w, oc[d4 * 4 + 3]);
                }
            }
            #pragma unroll
            for (int d = 0; d < 16; ++d) {
                oc[d] += __shfl_xor(oc[d], 1);
                oc[d] += __shfl_xor(oc[d], 2);
            }
            #pragma unroll
            for (int m = 0; m < 4; ++m) aoc[h][m] = oc[(jj << 2) + m] * inv;
            __syncthreads();
        }

        // attn out (heads concat) -> sH; stage Wo -> sW
        #pragma unroll
        for (int h = 0; h < 4; ++h)
            *(float4*)&sH[qq * LDW + h * 16 + (jj << 2)] =
                make_float4(aoc[h][0], aoc[h][1], aoc[h][2], aoc[h][3]);
        #pragma unroll
        for (int jq = 0; jq < 4; ++jq) {
            int qi = tid + jq * 256;
            int r = qi >> 4, cq = (qi & 15) << 2;
            *(float4*)&sW[r * LDW + cq] = LD4(&Wo[(size_t)l * 4096 + r * 64 + cq]);
        }
        __syncthreads();
        gemm64_acc(x, sH, sW, r0, c0);   // x += attn_out @ Wo
        __syncthreads();

        // h2 = LN2(x) -> sH
        ln_tile(x, sH, sLn + 128, sLn + 192, r0, c0);
        __syncthreads();

        // FF: x += relu(h2@W1 + b1)@W2 + b2, K-blocked by 64
        float fa[4][4];
        #pragma unroll
        for (int i = 0; i < 4; ++i) { fa[i][0] = 0.f; fa[i][1] = 0.f; fa[i][2] = 0.f; fa[i][3] = 0.f; }
        #pragma unroll 1
        for (int kb = 0; kb < 4; ++kb) {
            #pragma unroll
            for (int jq = 0; jq < 4; ++jq) {
                int qi = tid + jq * 256;
                int r = qi >> 4, cq = (qi & 15) << 2;
                *(float4*)&sW[r * LDW + cq] = LD4(&W1[(size_t)l * 16384 + r * 256 + kb * 64 + cq]);
            }
            __syncthreads();
            float t[4][4];
            #pragma unroll
            for (int i = 0; i < 4; ++i) { t[i][0] = 0.f; t[i][1] = 0.f; t[i][2] = 0.f; t[i][3] = 0.f; }
            gemm64_acc(t, sH, sW, r0, c0);
            #pragma unroll
            for (int i = 0; i < 4; ++i) {
                float4 tv;
                tv.x = fmaxf(t[i][0] + sB1[kb * 64 + c0 + 0], 0.f);
                tv.y = fmaxf(t[i][1] + sB1[kb * 64 + c0 + 1], 0.f);
                tv.z = fmaxf(t[i][2] + sB1[kb * 64 + c0 + 2], 0.f);
                tv.w = fmaxf(t[i][3] + sB1[kb * 64 + c0 + 3], 0.f);
                *(float4*)&sM[(r0 + i) * LDW + c0] = tv;
            }
            __syncthreads();
            #pragma unroll
            for (int jq = 0; jq < 4; ++jq) {
                int qi = tid + jq * 256;
                int r = qi >> 4, cq = (qi & 15) << 2;
                *(float4*)&sW[r * LDW + cq] = LD4(&W2[(size_t)l * 16384 + (kb * 64 + r) * 64 + cq]);
            }
            __syncthreads();
            gemm64_acc(fa, sM, sW, r0, c0);
            __syncthreads();
        }
        #pragma unroll
        for (int i = 0; i < 4; ++i) {
            x[i][0] += fa[i][0] + sB2[c0 + 0];
            x[i][1] += fa[i][1] + sB2[c0 + 1];
            x[i][2] += fa[i][2] + sB2[c0 + 2];
            x[i][3] += fa[i][3] + sB2[c0 + 3];
        }
    }

    // output row x[lidx] -> xrow (ws)
    if ((lidx >> 2) == tr) {
        float ov[4] = {0.f, 0.f, 0.f, 0.f};
        #pragma unroll
        for (int i = 0; i < 4; ++i)
            if ((lidx & 3) == i) { ov[0] = x[i][0]; ov[1] = x[i][1]; ov[2] = x[i][2]; ov[3] = x[i][3]; }
        *(float4*)&xrow[(size_t)b * 64 + c0] = make_float4(ov[0], ov[1], ov[2], ov[3]);
    }
}

__device__ __forceinline__ float softplusf(float v) {
    return fmaxf(v, 0.f) + log1pf(expf(-fabsf(v)));
}

__global__ __launch_bounds__(256) void policy_kernel(const float* __restrict__ xrow,
        const float* __restrict__ Wp1, const float* __restrict__ bp1,
        const float* __restrict__ Wp2, const float* __restrict__ bp2,
        float* __restrict__ outMu, float* __restrict__ outStd) {
    __shared__ float sx[64];
    __shared__ float sh1[256];
    const int tid = threadIdx.x;
    for (int bi = 0; bi < 16; ++bi) {
        int b = blockIdx.x * 16 + bi;
        if (tid < 64) sx[tid] = xrow[(size_t)b * 64 + tid];
        __syncthreads();
        float acc = bp1[tid];
        #pragma unroll 16
        for (int k = 0; k < 64; ++k) acc = fmaf(sx[k], Wp1[k * 256 + tid], acc);
        sh1[tid] = fmaxf(acc, 0.f);
        __syncthreads();
        if (tid < 224) {
            int j = tid >> 4, g = tid & 15;
            float a = 0.f;
            #pragma unroll
            for (int kk = 0; kk < 16; ++kk) {
                int k = g * 16 + kk;
                a = fmaf(sh1[k], Wp2[k * 14 + j], a);
            }
            a += __shfl_xor(a, 1); a += __shfl_xor(a, 2);
            a += __shfl_xor(a, 4); a += __shfl_xor(a, 8);
            if (g == 0) {
                float pol = a + bp2[j];
                if (j < 7) outStd[(size_t)b * 7 + j] = softplusf(pol);
                else       outMu[(size_t)b * 7 + (j - 7)] = tanhf(pol);
            }
        }
        __syncthreads();
    }
}

extern "C" void kernel_launch(void* const* d_in, const int* in_sizes, int n_in,
                              void* d_out, int out_size, void* d_ws, size_t ws_size,
                              hipStream_t stream) {
    const float* obs   = (const float*)d_in[0];
    const float* seqIn = (const float*)d_in[1];
    const float* mem   = (const float*)d_in[2];
    const int*   len   = (const int*)d_in[3];
    const float* ln_g  = (const float*)d_in[4];
    const float* ln_b  = (const float*)d_in[5];
    const float* Wemb  = (const float*)d_in[6];
    const float* ln1g  = (const float*)d_in[7];
    const float* ln1b  = (const float*)d_in[8];
    const float* ln2g  = (const float*)d_in[9];
    const float* ln2b  = (const float*)d_in[10];
    const float* Wq    = (const float*)d_in[11];
    const float* Wk    = (const float*)d_in[12];
    const float* Wv    = (const float*)d_in[13];
    const float* Wo    = (const float*)d_in[14];
    const float* W1    = (const float*)d_in[15];
    const float* b1    = (const float*)d_in[16];
    const float* W2    = (const float*)d_in[17];
    const float* b2    = (const float*)d_in[18];
    const float* Wp1   = (const float*)d_in[19];
    const float* bp1   = (const float*)d_in[20];
    const float* Wp2   = (const float*)d_in[21];
    const float* bp2   = (const float*)d_in[22];

    float* out    = (float*)d_out;
    float* outMu  = out;
    float* outStd = out + O_STD;
    float* outSeq = out + O_SEQ;
    float* outMem = out + O_MEM;
    float* outLen = out + O_LEN;
    float* xrow   = (float*)d_ws;   // 2048*64 floats = 512 KB scratch

    hipLaunchKernelGGL(copy4_kernel, dim3(19200), dim3(256), 0, stream,
                       (const float4*)seqIn, (float4*)outSeq, 4915200);
    hipLaunchKernelGGL(obs_ln_kernel, dim3(512), dim3(256), 0, stream,
                       obs, ln_g, ln_b, len, outSeq, outLen);
    hipLaunchKernelGGL(mega_kernel, dim3(2048), dim3(256), 0, stream,
                       outSeq, mem, len, Wemb, ln1g, ln1b, ln2g, ln2b,
                       Wq, Wk, Wv, Wo, W1, b1, W2, b2, outMem, xrow);
    hipLaunchKernelGGL(policy_kernel, dim3(128), dim3(256), 0, stream,
                       xrow, Wp1, bp1, Wp2, bp2, outMu, outStd);
}

// Round 3
// 650.702 us; speedup vs baseline: 4.8052x; 4.8052x over previous
//
#include <hip/hip_runtime.h>
#include <math.h>

// B=2048 S=64 D=6 H=4 DM=64 SS=150 A=7 HID=256 FF=256 DH=16
#define NB 2048

#define LD4(p) (*(const float4*)(p))

// out layout (floats): mu[14336] std[14336] seq[19660800] mem[50331648] len[2048]
#define O_STD 14336
#define O_SEQ 28672
#define O_MEM 19689472
#define O_LEN 70021120

// ws layout: xrow fp32 [2048*64] at byte 0 (512KB); bf16 weights at byte 524288.
// bf16-elem offsets inside the weight pool:
#define WQT 0
#define WKT 24576
#define WVT 49152
#define WOT 73728
#define W1T 98304
#define W2T 196608
#define WET 294912
// WET size 10240 -> total 305152 bf16 (610KB). ws use ~1.1MB.

typedef __attribute__((ext_vector_type(8))) short short8v;  // 8 bf16 = 4 VGPRs
typedef __attribute__((ext_vector_type(4))) float f32x4;

#define MFMA(a, b, c) __builtin_amdgcn_mfma_f32_16x16x32_bf16((a), (b), (c), 0, 0, 0)

__device__ __forceinline__ short f2bf(float f) {
    union { float f; unsigned u; } v; v.f = f;
    unsigned r = v.u + 0x7FFFu + ((v.u >> 16) & 1u);   // RNE
    return (short)(r >> 16);
}

// ---------------- prep: fp32 weights -> bf16 transposed in ws ----------------
__global__ __launch_bounds__(256) void prep_weights(
        const float* __restrict__ Wq, const float* __restrict__ Wk,
        const float* __restrict__ Wv, const float* __restrict__ Wo,
        const float* __restrict__ W1, const float* __restrict__ W2,
        const float* __restrict__ Wemb, short* __restrict__ wsb) {
    int idx = blockIdx.x * 256 + threadIdx.x;          // grid covers 98304
    // big: W1T [256n][64k], W2T [64n][256k]
    {
        int l = idx >> 14, r = idx & 16383;
        { int n = r >> 6, k = r & 63;
          wsb[W1T + idx] = f2bf(W1[l * 16384 + k * 256 + n]); }
        { int n = r >> 8, k = r & 255;
          wsb[W2T + idx] = f2bf(W2[l * 16384 + k * 64 + n]); }
    }
    if (idx < 24576) {                                  // 4 square mats [64n][64k]
        int l = idx >> 12, r = idx & 4095;
        int n = r >> 6, k = r & 63;
        int s = l * 4096 + k * 64 + n;
        wsb[WQT + idx] = f2bf(Wq[s]);
        wsb[WKT + idx] = f2bf(Wk[s]);
        wsb[WVT + idx] = f2bf(Wv[s]);
        wsb[WOT + idx] = f2bf(Wo[s]);
    }
    if (idx < 10240) {                                  // WembT [64n][160k]
        int n = idx / 160, k = idx - n * 160;
        wsb[WET + idx] = (k < 150) ? f2bf(Wemb[k * 64 + n]) : (short)0;
    }
}

// ---------------- small kernels (unchanged from fp32 baseline) ----------------
__global__ __launch_bounds__(256) void copy4_kernel(const float4* __restrict__ src,
                                                    float4* __restrict__ dst, int n) {
    int i = blockIdx.x * 256 + threadIdx.x;
    if (i < n) dst[i] = src[i];
}

__global__ __launch_bounds__(256) void obs_ln_kernel(const float* __restrict__ obs,
        const float* __restrict__ g, const float* __restrict__ be,
        const int* __restrict__ len, float* __restrict__ outSeq, float* __restrict__ outLen) {
    int w = threadIdx.x >> 6, lane = threadIdx.x & 63;
    int b = blockIdx.x * 4 + w;
    const float* row = obs + (size_t)b * 150;
    float v0 = row[lane], v1 = row[64 + lane];
    float v2 = (lane < 22) ? row[128 + lane] : 0.f;
    float s = v0 + v1 + v2;
    #pragma unroll
    for (int m = 1; m <= 32; m <<= 1) s += __shfl_xor(s, m);
    float mean = s * (1.0f / 150.0f);
    float d0 = v0 - mean, d1 = v1 - mean;
    float d2 = (lane < 22) ? (v2 - mean) : 0.f;
    float q = d0 * d0 + d1 * d1 + d2 * d2;
    #pragma unroll
    for (int m = 1; m <= 32; m <<= 1) q += __shfl_xor(q, m);
    float rs = rsqrtf(q * (1.0f / 150.0f) + 1e-5f);
    int lenraw = len[b];
    int lidx = min(max(lenraw, 0), 63);
    float* orow = outSeq + ((size_t)lidx * NB + b) * 150;
    orow[lane]      = d0 * rs * g[lane] + be[lane];
    orow[64 + lane] = d1 * rs * g[64 + lane] + be[64 + lane];
    if (lane < 22) orow[128 + lane] = d2 * rs * g[128 + lane] + be[128 + lane];
    if (lane == 0) outLen[b] = (float)((lenraw + 1) & 63);
}

// ---------------- MFMA mega kernel ----------------
// LDS arena L[20480] bf16 (40KB), region plan per phase:
//  R0 = L[0..8191]      : sKV (mem rows 0-63, h rows 64-127) / sK / [WoT @0-4095, sH2 @4096-8191]
//  R1 = L[8192..12287]  : WqT / sQ / sO / sW2T
//  R2 = L[12288..20479] : WkT+WvT / sVh[4][128][16] / [sW1T @12288, sT @16384]
__global__ __launch_bounds__(256, 2) void mega_kernel(
        const float* __restrict__ seq, const float* __restrict__ memory,
        const int* __restrict__ len,
        const float* __restrict__ ln1g, const float* __restrict__ ln1b,
        const float* __restrict__ ln2g, const float* __restrict__ ln2b,
        const float* __restrict__ b1, const float* __restrict__ b2,
        const short* __restrict__ wsb,
        float* __restrict__ memOut, float* __restrict__ xrow) {
    __shared__ short L[20480];
    __shared__ float fls[576];  // ln1g/ln1b/ln2g/ln2b (4*64) | b1f(256) | b2f(64)
    float* lnp = fls;
    float* b1f = fls + 256;
    float* b2f = fls + 512;

    const int tid = threadIdx.x;
    const int b = blockIdx.x;
    const int w = tid >> 6;          // wave = output row-tile / attention head
    const int lane = tid & 63;
    const int g = lane >> 4;         // 16-lane group
    const int r16 = lane & 15;

    const int lenraw = len[b];
    const int lidx = min(max(lenraw, 0), 63);
    const bool reset = (((lenraw + 1) & 63) == 0);

    const short8v zs = {0, 0, 0, 0, 0, 0, 0, 0};
    const f32x4 zf = {0.f, 0.f, 0.f, 0.f};

    // ---------------- embedding: x = seqB(64x150) @ Wemb ----------------
    // stage seq rows as bf16 [64][160] at L[0]; WembT [64][160] at L[10240]
    #pragma unroll 1
    for (int j = 0; j < 16; ++j) {
        int r = w * 16 + j;
        const float* srow = seq + ((size_t)r * NB + b) * 150;
        L[r * 160 + lane]      = f2bf(srow[lane]);
        L[r * 160 + 64 + lane] = f2bf(srow[64 + lane]);
        if (lane < 22)      L[r * 160 + 128 + lane] = f2bf(srow[128 + lane]);
        else if (lane < 32) L[r * 160 + 128 + lane] = 0;
    }
    {
        const int4* s = (const int4*)(wsb + WET);
        int4* d = (int4*)(L + 10240);
        #pragma unroll
        for (int i = 0; i < 5; ++i) d[tid + i * 256] = s[tid + i * 256];
    }
    __syncthreads();

    f32x4 x[4] = {zf, zf, zf, zf};
    #pragma unroll
    for (int kk = 0; kk < 5; ++kk) {
        short8v a = *(const short8v*)&L[(16 * w + r16) * 160 + kk * 32 + 8 * g];
        #pragma unroll
        for (int ct = 0; ct < 4; ++ct) {
            short8v bb = *(const short8v*)&L[10240 + (16 * ct + r16) * 160 + kk * 32 + 8 * g];
            x[ct] = MFMA(a, bb, x[ct]);
        }
    }
    __syncthreads();

    // ---------------- 6 transformer layers ----------------
    #pragma unroll 1
    for (int l = 0; l < 6; ++l) {
        // ---- stage phase ----
        if (tid < 64) {
            lnp[tid]       = ln1g[l * 64 + tid];
            lnp[64 + tid]  = ln1b[l * 64 + tid];
            lnp[128 + tid] = ln2g[l * 64 + tid];
            lnp[192 + tid] = ln2b[l * 64 + tid];
            b2f[tid]       = b2[l * 64 + tid];
        }
        b1f[tid] = b1[l * 256 + tid];
        {   // mem -> sKV rows 0..63 (bf16) + memOut passthrough (fp32, exact)
            const float* gmem = memory + ((size_t)l * NB + b) * 4096;
            float* gout = memOut + ((size_t)l * NB + b) * 4096;
            int rr = tid >> 2, c0 = (tid & 3) * 16;
            #pragma unroll
            for (int k4 = 0; k4 < 4; ++k4) {
                float4 v = LD4(&gmem[rr * 64 + c0 + k4 * 4]);
                if (!reset) *(float4*)&gout[rr * 64 + c0 + k4 * 4] = v;
                short4 sv;
                sv.x = f2bf(v.x); sv.y = f2bf(v.y); sv.z = f2bf(v.z); sv.w = f2bf(v.w);
                *(short4*)&L[rr * 64 + c0 + k4 * 4] = sv;
            }
            if (reset) {   // memOut = x (hidden entering this layer)
                #pragma unroll
                for (int ct = 0; ct < 4; ++ct)
                    #pragma unroll
                    for (int j = 0; j < 4; ++j)
                        gout[(16 * w + 4 * g + j) * 64 + 16 * ct + r16] = x[ct][j];
            }
        }
        {   // stage WqT/WkT/WvT -> R1 / R2
            const int4* sq = (const int4*)(wsb + WQT + l * 4096);
            const int4* sk = (const int4*)(wsb + WKT + l * 4096);
            const int4* sv = (const int4*)(wsb + WVT + l * 4096);
            int4* dq = (int4*)(L + 8192);
            int4* dk = (int4*)(L + 12288);
            int4* dv = (int4*)(L + 16384);
            #pragma unroll
            for (int i = 0; i < 2; ++i) {
                dq[tid + i * 256] = sq[tid + i * 256];
                dk[tid + i * 256] = sk[tid + i * 256];
                dv[tid + i * 256] = sv[tid + i * 256];
            }
        }
        __syncthreads();   // S1a: lnp visible

        // ---- LN1(x) -> sKV rows 64..127 (bf16) ----
        #pragma unroll
        for (int j = 0; j < 4; ++j) {
            float s = x[0][j] + x[1][j] + x[2][j] + x[3][j];
            s += __shfl_xor(s, 1); s += __shfl_xor(s, 2);
            s += __shfl_xor(s, 4); s += __shfl_xor(s, 8);
            float m = s * 0.015625f;
            float q = 0.f;
            #pragma unroll
            for (int ct = 0; ct < 4; ++ct) { float d = x[ct][j] - m; q += d * d; }
            q += __shfl_xor(q, 1); q += __shfl_xor(q, 2);
            q += __shfl_xor(q, 4); q += __shfl_xor(q, 8);
            float rs = rsqrtf(q * 0.015625f + 1e-5f);
            #pragma unroll
            for (int ct = 0; ct < 4; ++ct) {
                int col = 16 * ct + r16;
                float hv = (x[ct][j] - m) * rs * lnp[col] + lnp[64 + col];
                L[(64 + 16 * w + 4 * g + j) * 64 + col] = f2bf(hv);
            }
        }
        __syncthreads();   // S1b

        // ---- QKV GEMMs ----
        f32x4 qa[4] = {zf, zf, zf, zf};
        f32x4 ka[2][4] = {{zf, zf, zf, zf}, {zf, zf, zf, zf}};
        f32x4 va[2][4] = {{zf, zf, zf, zf}, {zf, zf, zf, zf}};
        #pragma unroll
        for (int kk = 0; kk < 2; ++kk) {
            short8v ah = *(const short8v*)&L[(64 + 16 * w + r16) * 64 + kk * 32 + 8 * g]; // h rows
            short8v a0 = *(const short8v*)&L[(16 * w + r16) * 64 + kk * 32 + 8 * g];       // mem rows
            #pragma unroll
            for (int ct = 0; ct < 4; ++ct) {
                short8v bq = *(const short8v*)&L[8192  + (16 * ct + r16) * 64 + kk * 32 + 8 * g];
                short8v bk = *(const short8v*)&L[12288 + (16 * ct + r16) * 64 + kk * 32 + 8 * g];
                short8v bv = *(const short8v*)&L[16384 + (16 * ct + r16) * 64 + kk * 32 + 8 * g];
                qa[ct]    = MFMA(ah, bq, qa[ct]);
                ka[0][ct] = MFMA(a0, bk, ka[0][ct]);
                ka[1][ct] = MFMA(ah, bk, ka[1][ct]);
                va[0][ct] = MFMA(a0, bv, va[0][ct]);
                va[1][ct] = MFMA(ah, bv, va[1][ct]);
            }
        }
        __syncthreads();   // S2

        // ---- pack Q -> R1 [64][64], K -> R0 [128][64], V -> R2 sVh[h][128][16] ----
        #pragma unroll
        for (int ct = 0; ct < 4; ++ct) {
            #pragma unroll
            for (int j = 0; j < 4; ++j) {
                int key0 = 16 * w + 4 * g + j;
                int key1 = 64 + key0;
                L[8192 + key0 * 64 + 16 * ct + r16] = f2bf(qa[ct][j]);
                L[key0 * 64 + 16 * ct + r16] = f2bf(ka[0][ct][j]);
                L[key1 * 64 + 16 * ct + r16] = f2bf(ka[1][ct][j]);
                L[12288 + ct * 2048 + key0 * 16 + r16] = f2bf(va[0][ct][j]);
                L[12288 + ct * 2048 + key1 * 16 + r16] = f2bf(va[1][ct][j]);
            }
        }
        __syncthreads();   // S3

        // ---- attention: wave w = head; S^T = K.Q^T ; O^T = V^T.P^T ----
        const int hc = 16 * w;
        f32x4 ofull[4] = {zf, zf, zf, zf};   // O^T tiles per q-tile
        #pragma unroll
        for (int qh = 0; qh < 2; ++qh) {
            short8v bQ[2];
            #pragma unroll
            for (int q2 = 0; q2 < 2; ++q2) {
                int qt = 2 * qh + q2;
                bQ[q2] = (g < 2) ? *(const short8v*)&L[8192 + (16 * qt + r16) * 64 + hc + 8 * g] : zs;
            }
            f32x4 s[8][2];
            #pragma unroll
            for (int kt = 0; kt < 8; ++kt) { s[kt][0] = zf; s[kt][1] = zf; }
            #pragma unroll
            for (int kt = 0; kt < 8; ++kt) {
                short8v aK = (g < 2) ? *(const short8v*)&L[(16 * kt + r16) * 64 + hc + 8 * g] : zs;
                s[kt][0] = MFMA(aK, bQ[0], s[kt][0]);
                s[kt][1] = MFMA(aK, bQ[1], s[kt][1]);
            }
            // scale + mask + softmax (per q column; values spread over g-groups)
            #pragma unroll
            for (int q2 = 0; q2 < 2; ++q2) {
                int q = 16 * (2 * qh + q2) + r16;
                float mx = -1e30f;
                #pragma unroll
                for (int kt = 0; kt < 8; ++kt)
                    #pragma unroll
                    for (int j = 0; j < 4; ++j) {
                        int key = 16 * kt + 4 * g + j;
                        float v = s[kt][q2][j] * 0.25f;
                        if (key >= 64 && (key - 64) > q) v = -1e30f;
                        s[kt][q2][j] = v;
                        mx = fmaxf(mx, v);
                    }
                mx = fmaxf(mx, __shfl_xor(mx, 16));
                mx = fmaxf(mx, __shfl_xor(mx, 32));
                float sum = 0.f;
                #pragma unroll
                for (int kt = 0; kt < 8; ++kt)
                    #pragma unroll
                    for (int j = 0; j < 4; ++j) {
                        float e = __expf(s[kt][q2][j] - mx);
                        s[kt][q2][j] = e; sum += e;
                    }
                sum += __shfl_xor(sum, 16);
                sum += __shfl_xor(sum, 32);
                float inv = 1.0f / sum;
                #pragma unroll
                for (int kt = 0; kt < 8; ++kt)
                    #pragma unroll
                    for (int j = 0; j < 4; ++j) s[kt][q2][j] *= inv;
            }
            // PV: A = V^T fragment (scalar b16 gathers), B = P^T from S regs
            #pragma unroll
            for (int kt2 = 0; kt2 < 4; ++kt2) {
                short8v aV;
                #pragma unroll
                for (int e = 0; e < 8; ++e) {
                    int key = 32 * kt2 + 16 * (e >> 2) + 4 * g + (e & 3);
                    aV[e] = L[12288 + w * 2048 + key * 16 + r16];
                }
                #pragma unroll
                for (int q2 = 0; q2 < 2; ++q2) {
                    short8v pb;
                    #pragma unroll
                    for (int e = 0; e < 8; ++e)
                        pb[e] = f2bf(s[2 * kt2 + (e >> 2)][q2][e & 3]);
                    ofull[2 * qh + q2] = MFMA(aV, pb, ofull[2 * qh + q2]);
                }
            }
        }
        __syncthreads();   // S4: attention LDS reads done

        // ---- write O -> R1 [64 q][64 d]; stage WoT -> R0p1 ----
        #pragma unroll
        for (int qt = 0; qt < 4; ++qt)
            #pragma unroll
            for (int j = 0; j < 4; ++j)
                L[8192 + (16 * qt + r16) * 64 + hc + 4 * g + j] = f2bf(ofull[qt][j]);
        {
            const int4* s = (const int4*)(wsb + WOT + l * 4096);
            int4* d = (int4*)(L + 0);
            #pragma unroll
            for (int i = 0; i < 2; ++i) d[tid + i * 256] = s[tid + i * 256];
        }
        __syncthreads();   // S5

        // ---- x += O @ Wo ----
        #pragma unroll
        for (int kk = 0; kk < 2; ++kk) {
            short8v a = *(const short8v*)&L[8192 + (16 * w + r16) * 64 + kk * 32 + 8 * g];
            #pragma unroll
            for (int ct = 0; ct < 4; ++ct) {
                short8v bb = *(const short8v*)&L[0 + (16 * ct + r16) * 64 + kk * 32 + 8 * g];
                x[ct] = MFMA(a, bb, x[ct]);
            }
        }
        // ---- LN2(x) -> sH2 at R0p2 (L[4096..8191]) ----
        #pragma unroll
        for (int j = 0; j < 4; ++j) {
            float s = x[0][j] + x[1][j] + x[2][j] + x[3][j];
            s += __shfl_xor(s, 1); s += __shfl_xor(s, 2);
            s += __shfl_xor(s, 4); s += __shfl_xor(s, 8);
            float m = s * 0.015625f;
            float q = 0.f;
            #pragma unroll
            for (int ct = 0; ct < 4; ++ct) { float d = x[ct][j] - m; q += d * d; }
            q += __shfl_xor(q, 1); q += __shfl_xor(q, 2);
            q += __shfl_xor(q, 4); q += __shfl_xor(q, 8);
            float rs = rsqrtf(q * 0.015625f + 1e-5f);
            #pragma unroll
            for (int ct = 0; ct < 4; ++ct) {
                int col = 16 * ct + r16;
                float hv = (x[ct][j] - m) * rs * lnp[128 + col] + lnp[192 + col];
                L[4096 + (16 * w + 4 * g + j) * 64 + col] = f2bf(hv);
            }
        }
        __syncthreads();   // S6

        // ---- FF: x += relu(h2@W1+b1)@W2 (+b2 after loop), K-blocked by 64 ----
        #pragma unroll 1
        for (int kb = 0; kb < 4; ++kb) {
            {   // stage sW1T chunk -> L[12288], sW2T chunk -> L[8192]
                const int4* s1 = (const int4*)(wsb + W1T + l * 16384 + kb * 4096);
                int4* d1 = (int4*)(L + 12288);
                #pragma unroll
                for (int i = 0; i < 2; ++i) d1[tid + i * 256] = s1[tid + i * 256];
                int4* d2 = (int4*)(L + 8192);
                #pragma unroll
                for (int i = 0; i < 2; ++i) {
                    int idx = tid + i * 256;            // 512 int4
                    int n = idx >> 3, c = idx & 7;
                    d2[idx] = *(const int4*)&wsb[W2T + l * 16384 + n * 256 + kb * 64 + c * 8];
                }
            }
            __syncthreads();   // S7
            f32x4 tacc[4] = {zf, zf, zf, zf};
            #pragma unroll
            for (int kk = 0; kk < 2; ++kk) {
                short8v a = *(const short8v*)&L[4096 + (16 * w + r16) * 64 + kk * 32 + 8 * g];
                #pragma unroll
                for (int ct = 0; ct < 4; ++ct) {
                    short8v bb = *(const short8v*)&L[12288 + (16 * ct + r16) * 64 + kk * 32 + 8 * g];
                    tacc[ct] = MFMA(a, bb, tacc[ct]);
                }
            }
            #pragma unroll
            for (int ct = 0; ct < 4; ++ct)
                #pragma unroll
                for (int j = 0; j < 4; ++j) {
                    float v = fmaxf(tacc[ct][j] + b1f[kb * 64 + 16 * ct + r16], 0.f);
                    L[16384 + (16 * w + 4 * g + j) * 64 + 16 * ct + r16] = f2bf(v);
                }
            __syncthreads();   // S8
            #pragma unroll
            for (int kk = 0; kk < 2; ++kk) {
                short8v a = *(const short8v*)&L[16384 + (16 * w + r16) * 64 + kk * 32 + 8 * g];
                #pragma unroll
                for (int ct = 0; ct < 4; ++ct) {
                    short8v bb = *(const short8v*)&L[8192 + (16 * ct + r16) * 64 + kk * 32 + 8 * g];
                    x[ct] = MFMA(a, bb, x[ct]);
                }
            }
            __syncthreads();   // S9
        }
        #pragma unroll
        for (int ct = 0; ct < 4; ++ct)
            #pragma unroll
            for (int j = 0; j < 4; ++j) x[ct][j] += b2f[16 * ct + r16];
    }

    // ---- output row x[lidx] -> xrow ----
    if (w == (lidx >> 4) && g == ((lidx >> 2) & 3)) {
        int j = lidx & 3;
        #pragma unroll
        for (int ct = 0; ct < 4; ++ct) {
            float v = (j == 0) ? x[ct][0] : (j == 1) ? x[ct][1] : (j == 2) ? x[ct][2] : x[ct][3];
            xrow[(size_t)b * 64 + 16 * ct + r16] = v;
        }
    }
}

__device__ __forceinline__ float softplusf(float v) {
    return fmaxf(v, 0.f) + log1pf(expf(-fabsf(v)));
}

__global__ __launch_bounds__(256) void policy_kernel(const float* __restrict__ xrow,
        const float* __restrict__ Wp1, const float* __restrict__ bp1,
        const float* __restrict__ Wp2, const float* __restrict__ bp2,
        float* __restrict__ outMu, float* __restrict__ outStd) {
    __shared__ float sx[64];
    __shared__ float sh1[256];
    const int tid = threadIdx.x;
    for (int bi = 0; bi < 16; ++bi) {
        int b = blockIdx.x * 16 + bi;
        if (tid < 64) sx[tid] = xrow[(size_t)b * 64 + tid];
        __syncthreads();
        float acc = bp1[tid];
        #pragma unroll 16
        for (int k = 0; k < 64; ++k) acc = fmaf(sx[k], Wp1[k * 256 + tid], acc);
        sh1[tid] = fmaxf(acc, 0.f);
        __syncthreads();
        if (tid < 224) {
            int j = tid >> 4, gg = tid & 15;
            float a = 0.f;
            #pragma unroll
            for (int kk = 0; kk < 16; ++kk) {
                int k = gg * 16 + kk;
                a = fmaf(sh1[k], Wp2[k * 14 + j], a);
            }
            a += __shfl_xor(a, 1); a += __shfl_xor(a, 2);
            a += __shfl_xor(a, 4); a += __shfl_xor(a, 8);
            if (gg == 0) {
                float pol = a + bp2[j];
                if (j < 7) outStd[(size_t)b * 7 + j] = softplusf(pol);
                else       outMu[(size_t)b * 7 + (j - 7)] = tanhf(pol);
            }
        }
        __syncthreads();
    }
}

extern "C" void kernel_launch(void* const* d_in, const int* in_sizes, int n_in,
                              void* d_out, int out_size, void* d_ws, size_t ws_size,
                              hipStream_t stream) {
    const float* obs   = (const float*)d_in[0];
    const float* seqIn = (const float*)d_in[1];
    const float* mem   = (const float*)d_in[2];
    const int*   len   = (const int*)d_in[3];
    const float* ln_g  = (const float*)d_in[4];
    const float* ln_b  = (const float*)d_in[5];
    const float* Wemb  = (const float*)d_in[6];
    const float* ln1g  = (const float*)d_in[7];
    const float* ln1b  = (const float*)d_in[8];
    const float* ln2g  = (const float*)d_in[9];
    const float* ln2b  = (const float*)d_in[10];
    const float* Wq    = (const float*)d_in[11];
    const float* Wk    = (const float*)d_in[12];
    const float* Wv    = (const float*)d_in[13];
    const float* Wo    = (const float*)d_in[14];
    const float* W1    = (const float*)d_in[15];
    const float* b1    = (const float*)d_in[16];
    const float* W2    = (const float*)d_in[17];
    const float* b2    = (const float*)d_in[18];
    const float* Wp1   = (const float*)d_in[19];
    const float* bp1   = (const float*)d_in[20];
    const float* Wp2   = (const float*)d_in[21];
    const float* bp2   = (const float*)d_in[22];

    float* out    = (float*)d_out;
    float* outMu  = out;
    float* outStd = out + O_STD;
    float* outSeq = out + O_SEQ;
    float* outMem = out + O_MEM;
    float* outLen = out + O_LEN;
    float* xrow   = (float*)d_ws;                         // 512KB
    short* wsb    = (short*)((char*)d_ws + 524288);       // bf16 weight pool

    hipLaunchKernelGGL(prep_weights, dim3(384), dim3(256), 0, stream,
                       Wq, Wk, Wv, Wo, W1, W2, Wemb, wsb);
    hipLaunchKernelGGL(copy4_kernel, dim3(19200), dim3(256), 0, stream,
                       (const float4*)seqIn, (float4*)outSeq, 4915200);
    hipLaunchKernelGGL(obs_ln_kernel, dim3(512), dim3(256), 0, stream,
                       obs, ln_g, ln_b, len, outSeq, outLen);
    hipLaunchKernelGGL(mega_kernel, dim3(2048), dim3(256), 0, stream,
                       outSeq, mem, len, ln1g, ln1b, ln2g, ln2b, b1, b2,
                       wsb, outMem, xrow);
    hipLaunchKernelGGL(policy_kernel, dim3(128), dim3(256), 0, stream,
                       xrow, Wp1, bp1, Wp2, bp2, outMu, outStd);
}